// Round 8
// baseline (714.639 us; speedup 1.0000x reference)
//
#include <hip/hip_runtime.h>
#include <cstddef>

#define NPB  4096            // points per batch
#define KNB  20              // neighbors
#define NB   8               // batches
#define NPTS (NB * NPB)      // 32768 total points
#define NSEG 16              // segment-waves per block (R17: was 8)
#define SEGW 256             // candidates per segment  (R17: was 512)
#define NSLOT 16             // push-buffer slots per thread

// ---------------------------------------------------------------------------
// Kernel A+P (R15-validated): pack (x,y,z,xx) float4 + BN fold, w2f fold
// spread over 16 blocks with coalesced reads / scattered writes.
// ---------------------------------------------------------------------------
__global__ __launch_bounds__(256) void pack_prep_kernel(
    const float* __restrict__ x, float4* __restrict__ xp,
    const float* __restrict__ w1, const float* __restrict__ b1,
    const float* __restrict__ g1, const float* __restrict__ be1,
    const float* __restrict__ rm1, const float* __restrict__ rv1,
    const float* __restrict__ w2, const float* __restrict__ b2,
    const float* __restrict__ g2, const float* __restrict__ be2,
    const float* __restrict__ rm2, const float* __restrict__ rv2,
    float* __restrict__ w1f, float* __restrict__ w2f, float* __restrict__ w2b)
{
    const int tid = threadIdx.x;
    const int g = blockIdx.x * 256 + tid;
    const int b = g >> 12, n = g & (NPB - 1);
    const float* xb = x + (size_t)b * 3 * NPB;
    float a0 = xb[n], a1 = xb[NPB + n], a2 = xb[2 * NPB + n];
    float xx = __fadd_rn(__fadd_rn(__fmul_rn(a0, a0), __fmul_rn(a1, a1)),
                         __fmul_rn(a2, a2));
    xp[g] = make_float4(a0, a1, a2, xx);

    if (blockIdx.x == 0 && tid < 64) {
        float sc1 = g1[tid] * rsqrtf(rv1[tid] + 1e-5f);
        float sh1 = be1[tid] - rm1[tid] * sc1;
#pragma unroll
        for (int j = 0; j < 6; ++j) w1f[tid * 8 + j] = sc1 * w1[tid * 6 + j];
        w1f[tid * 8 + 6] = sc1 * b1[tid] + sh1;
        w1f[tid * 8 + 7] = 0.f;
        float sc2 = g2[tid] * rsqrtf(rv2[tid] + 1e-5f);
        w2b[tid] = sc2 * b2[tid] + (be2[tid] - rm2[tid] * sc2);
    }
    if (blockIdx.x < 16) {
#pragma unroll
        for (int r = 0; r < 2; ++r) {
            int j = blockIdx.x * 512 + r * 256 + tid;   // linear index into w2
            int o = j >> 7, c = j & 127;                // w2[o][c]
            float sc2 = g2[o] * rsqrtf(rv2[o] + 1e-5f);
            w2f[c * 64 + o] = sc2 * w2[j];
        }
    }
}

// ---------------------------------------------------------------------------
// Kernel B+C merged. R17 = R16 algorithms at 1024 threads / 16 segment-waves
// (SEGW 256): grid is 512 blocks = 2/CU, so 16-wave blocks give 32 waves/CU
// (HW max) vs 16 before — fills the ~30% VALU-idle measured through R16.
// New: staged 16-list merge (vals LDS reused twice, h1/h2 half-merges by
// wave 0, final 2-way per-thread; exact: global-top20 element from half h is
// in half-h's top-20). Survivor lists ushort (idx | strict<<15).
// LDS union = 80 KB (scan member), 2 blocks/CU = full 160 KB pool
// (R12 precedent: 81920 ran 2-resident). VGPR must stay <=64 -> bounds(1024,8).
// ---------------------------------------------------------------------------
union KSMem {
    struct {
        float  buf[NSLOT][1024];        // 64 KB scan push buffers [slot][tid]
        float4 shareV[NSEG][64];        // 16 KB {v20,v10,v5,-} per wave/pt
    } s;                                // 80 KB
    struct {
        float vals[8][KNB][64];         // 40 KB staged sorted lists (x2 use)
        float h1[KNB][64];              //  5 KB merged half 1 (segs 0-7)
        float h2[KNB][64];              //  5 KB merged half 2 (segs 8-15)
    } m;                                // 50 KB
    struct {
        unsigned short list[NSEG][64][22];  // 44 KB survivors (22: bank spread)
        unsigned short cnt[NSEG][64];       //  2 KB
    } b;                                // 46 KB
    struct {
        float cat[128 * 64];            // 32 KB [c][pt]: c<64 m1, c>=64 m2
        float dif[KNB][3][64];          // 15 KB [k][coord][pt]
    } f;                                // 47 KB
    struct {
        char pad[49664];                // above b (47104) and f (48128)
        unsigned short outk[KNB][64];   // 2.5 KB final neighbor idx
    } o;                                // overlaps only dead m.h2 region
};

__global__ __launch_bounds__(1024, 8) void knnfuse_kernel(
    const float4* __restrict__ xp,
    const float* __restrict__ w1f, const float* __restrict__ w2f,
    const float* __restrict__ w2b, float* __restrict__ out)
{
    __shared__ KSMem sm;

    const int tid  = threadIdx.x;
    const int wv   = __builtin_amdgcn_readfirstlane(tid >> 6);  // 0..15
    const int lane = tid & 63;
    const int g0   = blockIdx.x * 64;
    const int b    = g0 >> 12;
    const int n0   = g0 & (NPB - 1);

    sm.s.shareV[wv][lane] = make_float4(-INFINITY, -INFINITY, -INFINITY, 0.f);
    __syncthreads();

    const float4 me = xp[g0 + lane];                 // coalesced / L1
    const float cx = me.x, cy = me.y, cz = me.z, xxn = me.w;

    auto dist = [&](float4 q) -> float {
        float inner = __fadd_rn(__fadd_rn(__fmul_rn(cx, q.x), __fmul_rn(cy, q.y)),
                                __fmul_rn(cz, q.z));
        return __fsub_rn(__fsub_rn(__fmul_rn(2.0f, inner), xxn), q.w);
    };

    float vals[KNB];
#pragma unroll
    for (int j = 0; j < KNB; ++j) vals[j] = -INFINITY;

    const float4* cand = xp + (b << 12) + wv * SEGW; // wave-uniform -> s_load

    // warm-up: direct sorted insert of first 20 candidates (1-ahead prefetch)
    {
        float4 cw = cand[0];
#pragma unroll 1
        for (int i = 0; i < KNB; ++i) {
            float4 nxt = cand[i + 1];                // i+1 <= 20 < SEGW: safe
            float cv = dist(cw);
#pragma unroll
            for (int j = 0; j < KNB; ++j) {
                float nv = fmaxf(cv, vals[j]);
                cv       = fminf(cv, vals[j]);
                vals[j]  = nv;
            }
            cw = nxt;
        }
    }
    float vmin = vals[KNB - 1];
    float thr  = vmin;
    int   cnt  = 0;

    // (R16-J) publish {v20,v10,v5}; tighten thr with exact union bounds.
    // racy by design: stale stats are older (smaller) -> still <= t.
    auto refresh = [&]() {
        sm.s.shareV[wv][lane] = make_float4(vmin, vals[9], vals[4], 0.f);
        float4 s0 = sm.s.shareV[0][lane],  s1 = sm.s.shareV[1][lane];
        float4 s2 = sm.s.shareV[2][lane],  s3 = sm.s.shareV[3][lane];
        float4 s4 = sm.s.shareV[4][lane],  s5 = sm.s.shareV[5][lane];
        float4 s6 = sm.s.shareV[6][lane],  s7 = sm.s.shareV[7][lane];
        float4 s8 = sm.s.shareV[8][lane],  s9 = sm.s.shareV[9][lane];
        float4 sa = sm.s.shareV[10][lane], sb = sm.s.shareV[11][lane];
        float4 sc = sm.s.shareV[12][lane], sd = sm.s.shareV[13][lane];
        float4 se = sm.s.shareV[14][lane], sf = sm.s.shareV[15][lane];
        // 20 elems >= max of per-segment 20ths
        float m19 = fmaxf(
            fmaxf(fmaxf(fmaxf(s0.x, s1.x), fmaxf(s2.x, s3.x)),
                  fmaxf(fmaxf(s4.x, s5.x), fmaxf(s6.x, s7.x))),
            fmaxf(fmaxf(fmaxf(s8.x, s9.x), fmaxf(sa.x, sb.x)),
                  fmaxf(fmaxf(sc.x, sd.x), fmaxf(se.x, sf.x))));
        // pair bound: 2 segs x 10 elems >= min(v10 pair); 8 pairs
        float b9 = fmaxf(
            fmaxf(fmaxf(fminf(s0.y, s1.y), fminf(s2.y, s3.y)),
                  fmaxf(fminf(s4.y, s5.y), fminf(s6.y, s7.y))),
            fmaxf(fmaxf(fminf(s8.y, s9.y), fminf(sa.y, sb.y)),
                  fmaxf(fminf(sc.y, sd.y), fminf(se.y, sf.y))));
        // quad bound: 4 segs x 5 elems >= min(v5 quad); 4 quads
        float q0 = fminf(fminf(s0.z, s1.z), fminf(s2.z, s3.z));
        float q1 = fminf(fminf(s4.z, s5.z), fminf(s6.z, s7.z));
        float q2 = fminf(fminf(s8.z, s9.z), fminf(sa.z, sb.z));
        float q3 = fminf(fminf(sc.z, sd.z), fminf(se.z, sf.z));
        float b4 = fmaxf(fmaxf(q0, q1), fmaxf(q2, q3));
        thr = fmaxf(fmaxf(thr, m19), fmaxf(b9, b4));
    };
    refresh();                                       // early seed (lists full)

    auto flush = [&]() {
        float cv = sm.s.buf[0][tid];                 // speculative 1-ahead
#pragma unroll
        for (int j = 0; j < NSLOT; ++j) {
            if (!__any(j < cnt)) break;
            float nxt = (j + 1 < NSLOT) ? sm.s.buf[j + 1][tid] : -INFINITY;
            float c = (j < cnt) ? cv : -INFINITY;
            if (__any(c > vals[KNB - 1])) {          // (R16-K) stale-slot skip
#pragma unroll
                for (int q = 0; q < KNB; ++q) {      // 2-op step: max/min
                    float nv = fmaxf(c, vals[q]);
                    c        = fminf(c, vals[q]);
                    vals[q]  = nv;
                }
            }
            cv = nxt;
        }
        vmin = vals[KNB - 1];
        cnt = 0;
        thr = fmaxf(thr, vmin);
    };

    // remainder of first 64-cand chunk, buffered (<=12 resident + 4 = 16)
    {
        float4 c4[4];
#pragma unroll
        for (int u = 0; u < 4; ++u) c4[u] = cand[KNB + u];
#pragma unroll 1
        for (int i = KNB; i < 64; i += 4) {
            float4 n4[4];
            const int nx = (i + 4 < 64) ? i + 4 : KNB;   // clamp: safe reload
#pragma unroll
            for (int u = 0; u < 4; ++u) n4[u] = cand[nx + u];
            if ((i & 15) == 4) refresh();
#pragma unroll
            for (int u = 0; u < 4; ++u) {
                float d = dist(c4[u]);
                if (d > thr) { sm.s.buf[cnt][tid] = d; ++cnt; }
            }
            if (__any(cnt >= 13)) flush();
#pragma unroll
            for (int u = 0; u < 4; ++u) c4[u] = n4[u];
        }
    }
    flush();                                         // leave cnt=0 for main

    // main scan: refresh every 32, flush check every 8, ping-pong prefetch
    {
        float4 ca[8], cb[8];
#pragma unroll
        for (int u = 0; u < 8; ++u) ca[u] = cand[64 + u];
#pragma unroll 1
        for (int i = 64; i < SEGW; i += 16) {
#pragma unroll
            for (int u = 0; u < 8; ++u) cb[u] = cand[i + 8 + u];
            if ((i & 31) == 0) refresh();
#pragma unroll
            for (int u = 0; u < 8; ++u) {
                float d = dist(ca[u]);
                if (d > thr) { sm.s.buf[cnt][tid] = d; ++cnt; }
            }
            if (__any(cnt >= 9)) flush();            // <=8 resident + 8 = 16
            const int nx = (i + 16 < SEGW) ? i + 16 : 64;  // clamp: safe
#pragma unroll
            for (int u = 0; u < 8; ++u) ca[u] = cand[nx + u];
#pragma unroll
            for (int u = 0; u < 8; ++u) {
                float d = dist(cb[u]);
                if (d > thr) { sm.s.buf[cnt][tid] = d; ++cnt; }
            }
            if (__any(cnt >= 9)) flush();
        }
    }
    flush();
    __syncthreads();                                 // retire buf/shareV

    // ---------------- staged 16-list merge -> t (exact) --------------------
    // stage 1: segments 0-7 store; wave 0 8-way-merges into h1
    if (wv < 8) {
#pragma unroll
        for (int j = 0; j < KNB; ++j) sm.m.vals[wv][j][lane] = vals[j];
    }
    __syncthreads();
    if (wv == 0) {
        int p0 = 0, p1 = 0, p2 = 0, p3 = 0, p4 = 0, p5 = 0, p6 = 0, p7 = 0;
#pragma unroll 1
        for (int k = 0; k < KNB; ++k) {
            float e0 = sm.m.vals[0][p0][lane], e1 = sm.m.vals[1][p1][lane];
            float e2 = sm.m.vals[2][p2][lane], e3 = sm.m.vals[3][p3][lane];
            float e4 = sm.m.vals[4][p4][lane], e5 = sm.m.vals[5][p5][lane];
            float e6 = sm.m.vals[6][p6][lane], e7 = sm.m.vals[7][p7][lane];
            float bv = e0; int bs = 0;
            if (e1 > bv) { bv = e1; bs = 1; }
            if (e2 > bv) { bv = e2; bs = 2; }
            if (e3 > bv) { bv = e3; bs = 3; }
            if (e4 > bv) { bv = e4; bs = 4; }
            if (e5 > bv) { bv = e5; bs = 5; }
            if (e6 > bv) { bv = e6; bs = 6; }
            if (e7 > bv) { bv = e7; bs = 7; }
            sm.m.h1[k][lane] = bv;
            p0 += (bs == 0); p1 += (bs == 1); p2 += (bs == 2); p3 += (bs == 3);
            p4 += (bs == 4); p5 += (bs == 5); p6 += (bs == 6); p7 += (bs == 7);
        }
    }
    __syncthreads();
    // stage 2: segments 8-15 store over the same region; wave 0 merges -> h2
    if (wv >= 8) {
#pragma unroll
        for (int j = 0; j < KNB; ++j) sm.m.vals[wv - 8][j][lane] = vals[j];
    }
    __syncthreads();
    if (wv == 0) {
        int p0 = 0, p1 = 0, p2 = 0, p3 = 0, p4 = 0, p5 = 0, p6 = 0, p7 = 0;
#pragma unroll 1
        for (int k = 0; k < KNB; ++k) {
            float e0 = sm.m.vals[0][p0][lane], e1 = sm.m.vals[1][p1][lane];
            float e2 = sm.m.vals[2][p2][lane], e3 = sm.m.vals[3][p3][lane];
            float e4 = sm.m.vals[4][p4][lane], e5 = sm.m.vals[5][p5][lane];
            float e6 = sm.m.vals[6][p6][lane], e7 = sm.m.vals[7][p7][lane];
            float bv = e0; int bs = 0;
            if (e1 > bv) { bv = e1; bs = 1; }
            if (e2 > bv) { bv = e2; bs = 2; }
            if (e3 > bv) { bv = e3; bs = 3; }
            if (e4 > bv) { bv = e4; bs = 4; }
            if (e5 > bv) { bv = e5; bs = 5; }
            if (e6 > bv) { bv = e6; bs = 6; }
            if (e7 > bv) { bv = e7; bs = 7; }
            sm.m.h2[k][lane] = bv;
            p0 += (bs == 0); p1 += (bs == 1); p2 += (bs == 2); p3 += (bs == 3);
            p4 += (bs == 4); p5 += (bs == 5); p6 += (bs == 6); p7 += (bs == 7);
        }
    }
    __syncthreads();
    // final 2-way merge (all threads): t = 20th of union; p1+p2=k<=19 -> safe
    float t = -INFINITY;
    {
        int p1 = 0, p2 = 0;
#pragma unroll 1
        for (int k = 0; k < KNB; ++k) {
            float e1 = sm.m.h1[p1][lane];
            float e2 = sm.m.h2[p2][lane];
            bool tk2 = e2 > e1;                      // tie -> h1 (lower segs)
            t = tk2 ? e2 : e1;
            p2 += tk2 ? 1 : 0; p1 += tk2 ? 0 : 1;
        }
    }
    __syncthreads();                                 // retire h1/h2 (alias b)

    // phase B: collect survivors d >= t (ushort idx | strict<<15),
    // wave-uniform streamed re-scan with ping-pong prefetch
    int myc = 0;
    {
        float4 ca[8], cb[8];
#pragma unroll
        for (int u = 0; u < 8; ++u) ca[u] = cand[u];
#pragma unroll 1
        for (int i = 0; i < SEGW; i += 16) {
#pragma unroll
            for (int u = 0; u < 8; ++u) cb[u] = cand[i + 8 + u];
#pragma unroll
            for (int u = 0; u < 8; ++u) {
                float d = dist(ca[u]);
                if (d >= t) {
                    if (myc < KNB)
                        sm.b.list[wv][lane][myc] = (unsigned short)(
                            (wv * SEGW + i + u) | ((d > t) ? 0x8000 : 0));
                    ++myc;
                }
            }
            const int nx = (i + 16 < SEGW) ? i + 16 : 0;   // clamp: safe
#pragma unroll
            for (int u = 0; u < 8; ++u) ca[u] = cand[nx + u];
#pragma unroll
            for (int u = 0; u < 8; ++u) {
                float d = dist(cb[u]);
                if (d >= t) {
                    if (myc < KNB)
                        sm.b.list[wv][lane][myc] = (unsigned short)(
                            (wv * SEGW + i + 8 + u) | ((d > t) ? 0x8000 : 0));
                    ++myc;
                }
            }
        }
    }
    sm.b.cnt[wv][lane] = (unsigned short)((myc < KNB) ? myc : KNB);
    __syncthreads();

    // dedup (wave 0): strict survivors first, then ties, ascending seg order
    if (wv == 0) {
        int nout = 0;
#pragma unroll 1
        for (int pass = 0; pass < 2; ++pass) {       // 0: d>t, 1: d==t
#pragma unroll 1
            for (int w = 0; w < NSEG; ++w) {
                int cw = sm.b.cnt[w][lane];
#pragma unroll 1
                for (int j = 0; j < KNB; ++j) {
                    if (!__any(j < cw)) break;
                    if (j < cw) {
                        int e = sm.b.list[w][lane][j];
                        bool strict = (e & 0x8000) != 0;
                        bool take = (pass == 0) ? strict : !strict;
                        if (take && nout < KNB) {
                            sm.o.outk[nout][lane] = (unsigned short)(e & 0x0FFF);
                            ++nout;
                        }
                    }
                }
            }
        }
    }
    __syncthreads();                                 // outk ready; b dead

    // ------------------- fused conv epilogue -------------------------------
#pragma unroll
    for (int r = 0; r < 2; ++r) {
        int p = tid + r * 1024;
        if (p < KNB * 64) {
            int k = p >> 6, pt = p & 63;
            int nb = sm.o.outk[k][pt];
            float4 nq = xp[(b << 12) + nb];              // scattered (spread)
            float4 cq = xp[g0 + pt];                     // L1-hot
            sm.f.dif[k][0][pt] = __fsub_rn(nq.x, cq.x);
            sm.f.dif[k][1][pt] = __fsub_rn(nq.y, cq.y);
            sm.f.dif[k][2][pt] = __fsub_rn(nq.z, cq.z);
        }
    }
    __syncthreads();

    float dx[KNB], dy[KNB], dz[KNB];
#pragma unroll
    for (int k = 0; k < KNB; ++k) {                      // conflict-free LDS
        dx[k] = sm.f.dif[k][0][lane];
        dy[k] = sm.f.dif[k][1][lane];
        dz[k] = sm.f.dif[k][2][lane];
    }

    // conv1 sixteenth: channels [4*wv, 4*wv+4)
    const float4* w1fv = (const float4*)w1f;
#pragma unroll 1
    for (int cc = 0; cc < 4; ++cc) {
        int c = wv * 4 + cc;                             // uniform -> s_load
        float4 wa = w1fv[c * 2];                         // {W0,W1,W2,W3}
        float4 wb = w1fv[c * 2 + 1];                     // {W4,W5,B1',pad}
        float base = wb.z + wa.w * cx + wb.x * cy + wb.y * cz;
        float m1 = -INFINITY, s = 0.f;
#pragma unroll
        for (int k = 0; k < KNB; ++k) {
            float h = fmaf(dz[k], wa.z, fmaf(dy[k], wa.y, fmaf(dx[k], wa.x, base)));
            float r = fmaxf(0.f, h);
            m1 = fmaxf(m1, r);
            s += r;
        }
        sm.f.cat[c * 64 + lane]        = m1;
        sm.f.cat[(64 + c) * 64 + lane] = s / 20.0f;
    }
    __syncthreads();

    const size_t SEC = (size_t)NB * 64 * NPB;   // elements per output section

    // write m1/m2 rows straight from cat (coalesced 256B rows)
#pragma unroll 1
    for (int q = 0; q < 8; ++q) {
        int r  = wv * 8 + q;                    // 0..127, uniform
        int ch = r & 63;
        float* dst = out + SEC * (1 + (r >> 6)) + ((size_t)b * 64 + ch) * NPB + n0;
        dst[lane] = sm.f.cat[r * 64 + lane];
    }

    // conv2 sixteenth: outputs [4*wv, 4*wv+4)
    const int ob = wv * 4;                      // uniform -> s_load weights
    float acc[4];
#pragma unroll
    for (int j = 0; j < 4; ++j) acc[j] = w2b[ob + j];
#pragma unroll 4
    for (int c = 0; c < 128; ++c) {
        float v = sm.f.cat[c * 64 + lane];
        const float4* wr = (const float4*)(w2f + c * 64 + ob);
        float4 q0 = wr[0];
        acc[0] = fmaf(v, q0.x, acc[0]);  acc[1] = fmaf(v, q0.y, acc[1]);
        acc[2] = fmaf(v, q0.z, acc[2]);  acc[3] = fmaf(v, q0.w, acc[3]);
    }
#pragma unroll
    for (int j = 0; j < 4; ++j) acc[j] = fmaxf(0.f, acc[j]);

    __syncthreads();                            // all waves done reading cat
#pragma unroll
    for (int j = 0; j < 4; ++j) sm.f.cat[(ob + j) * 64 + lane] = acc[j];
    __syncthreads();
#pragma unroll 1
    for (int q = 0; q < 4; ++q) {
        int oo = wv * 4 + q;
        out[((size_t)b * 64 + oo) * NPB + n0 + lane] = sm.f.cat[oo * 64 + lane];
    }
}

extern "C" void kernel_launch(void* const* d_in, const int* in_sizes, int n_in,
                              void* d_out, int out_size, void* d_ws, size_t ws_size,
                              hipStream_t stream) {
    const float* x   = (const float*)d_in[0];
    const float* w1  = (const float*)d_in[1];
    const float* b1  = (const float*)d_in[2];
    const float* g1  = (const float*)d_in[3];
    const float* be1 = (const float*)d_in[4];
    const float* rm1 = (const float*)d_in[5];
    const float* rv1 = (const float*)d_in[6];
    const float* w2  = (const float*)d_in[7];
    const float* b2  = (const float*)d_in[8];
    const float* g2  = (const float*)d_in[9];
    const float* be2 = (const float*)d_in[10];
    const float* rm2 = (const float*)d_in[11];
    const float* rv2 = (const float*)d_in[12];

    char*   ws  = (char*)d_ws;
    float4* xp  = (float4*)ws;                      // 512 KB
    float*  w1f = (float*)(ws + 512 * 1024);        // 2 KB
    float*  w2f = w1f + 64 * 8;                     // 32 KB
    float*  w2b = w2f + 64 * 128;                   // 256 B

    pack_prep_kernel<<<NPTS / 256, 256, 0, stream>>>(
        x, xp, w1, b1, g1, be1, rm1, rv1, w2, b2, g2, be2, rm2, rv2,
        w1f, w2f, w2b);
    knnfuse_kernel<<<NPTS / 64, 1024, 0, stream>>>(xp, w1f, w2f, w2b,
                                                   (float*)d_out);
}

// Round 9
// 237.457 us; speedup vs baseline: 3.0096x; 3.0096x over previous
//
#include <hip/hip_runtime.h>
#include <cstddef>

#define NPB  4096            // points per batch
#define KNB  20              // neighbors
#define NB   8               // batches
#define NPTS (NB * NPB)      // 32768 total points
#define NSEG 8               // segment-waves per block
#define SEGW 512             // candidates per segment
#define NSLOT 16             // push-buffer slots per thread

// ---------------------------------------------------------------------------
// Kernel A+P (R15-validated): pack (x,y,z,xx) float4 + BN fold, w2f fold
// spread over 16 blocks with coalesced reads / scattered writes.
// ---------------------------------------------------------------------------
__global__ __launch_bounds__(256) void pack_prep_kernel(
    const float* __restrict__ x, float4* __restrict__ xp,
    const float* __restrict__ w1, const float* __restrict__ b1,
    const float* __restrict__ g1, const float* __restrict__ be1,
    const float* __restrict__ rm1, const float* __restrict__ rv1,
    const float* __restrict__ w2, const float* __restrict__ b2,
    const float* __restrict__ g2, const float* __restrict__ be2,
    const float* __restrict__ rm2, const float* __restrict__ rv2,
    float* __restrict__ w1f, float* __restrict__ w2f, float* __restrict__ w2b)
{
    const int tid = threadIdx.x;
    const int g = blockIdx.x * 256 + tid;
    const int b = g >> 12, n = g & (NPB - 1);
    const float* xb = x + (size_t)b * 3 * NPB;
    float a0 = xb[n], a1 = xb[NPB + n], a2 = xb[2 * NPB + n];
    float xx = __fadd_rn(__fadd_rn(__fmul_rn(a0, a0), __fmul_rn(a1, a1)),
                         __fmul_rn(a2, a2));
    xp[g] = make_float4(a0, a1, a2, xx);

    if (blockIdx.x == 0 && tid < 64) {
        float sc1 = g1[tid] * rsqrtf(rv1[tid] + 1e-5f);
        float sh1 = be1[tid] - rm1[tid] * sc1;
#pragma unroll
        for (int j = 0; j < 6; ++j) w1f[tid * 8 + j] = sc1 * w1[tid * 6 + j];
        w1f[tid * 8 + 6] = sc1 * b1[tid] + sh1;
        w1f[tid * 8 + 7] = 0.f;
        float sc2 = g2[tid] * rsqrtf(rv2[tid] + 1e-5f);
        w2b[tid] = sc2 * b2[tid] + (be2[tid] - rm2[tid] * sc2);
    }
    if (blockIdx.x < 16) {
#pragma unroll
        for (int r = 0; r < 2; ++r) {
            int j = blockIdx.x * 512 + r * 256 + tid;   // linear index into w2
            int o = j >> 7, c = j & 127;                // w2[o][c]
            float sc2 = g2[o] * rsqrtf(rv2[o] + 1e-5f);
            w2f[c * 64 + o] = sc2 * w2[j];
        }
    }
}

// ---------------------------------------------------------------------------
// Kernel B+C merged. R18 = R16 EXACT (measured 171.5us; R17's 1024-thread
// variant spilled to scratch — 734 MB HBM, 664us — and is abandoned) + one
// added threshold bound in refresh using the free shareV.w slot:
//  octet-v3 bound: b3 = min over all 8 segments of that segment's 3rd-best.
//  Every segment holds >=3 elements >= b3 -> >=24 >= 20 elements >= b3 ->
//  b3 <= t. At equality (thr == t via b3) the lists jointly hold >=24
//  elements >= t, so the merged 20th still equals t (same proof shape as
//  the shipped pair/quad bounds). Staleness monotone-safe as before.
// ---------------------------------------------------------------------------
union KSMem {
    float buf[NSLOT][512];          // 32 KB scan push buffers [slot][tid]
    float vals[NSEG][KNB][64];      // 40 KB sorted partial lists [wave][j][pt]
    struct {
        int list[NSEG][64][21];     // 42 KB survivors idx|(strict<<31)
        int cnt[NSEG][64];          //  2 KB
    } b;                            // 44 KB
    struct {
        float cat[128 * 64];        // 32 KB [c][pt]: c<64 m1, c>=64 m2
        float dif[KNB][3][64];      // 15 KB [k][coord][pt]
    } f;                            // 47 KB  (union = 47 KB)
};

__global__ __launch_bounds__(512, 4) void knnfuse_kernel(
    const float4* __restrict__ xp,
    const float* __restrict__ w1f, const float* __restrict__ w2f,
    const float* __restrict__ w2b, float* __restrict__ out)
{
    __shared__ KSMem sm;
    __shared__ float4 shareV[NSEG][64]; // 8 KB {v20, v10, v5, v3} per wave/pt
    __shared__ int   outk[KNB][64];     // 5 KB final neighbor idx [k][pt]

    const int tid  = threadIdx.x;
    const int wv   = __builtin_amdgcn_readfirstlane(tid >> 6);
    const int lane = tid & 63;
    const int g0   = blockIdx.x * 64;
    const int b    = g0 >> 12;
    const int n0   = g0 & (NPB - 1);

    shareV[wv][lane] = make_float4(-INFINITY, -INFINITY, -INFINITY, -INFINITY);
    __syncthreads();

    const float4 me = xp[g0 + lane];                 // coalesced
    const float cx = me.x, cy = me.y, cz = me.z, xxn = me.w;

    auto dist = [&](float4 q) -> float {
        float inner = __fadd_rn(__fadd_rn(__fmul_rn(cx, q.x), __fmul_rn(cy, q.y)),
                                __fmul_rn(cz, q.z));
        return __fsub_rn(__fsub_rn(__fmul_rn(2.0f, inner), xxn), q.w);
    };

    float vals[KNB];
#pragma unroll
    for (int j = 0; j < KNB; ++j) vals[j] = -INFINITY;

    const float4* cand = xp + (b << 12) + wv * SEGW; // wave-uniform -> s_load

    // warm-up: direct sorted insert of first 20 candidates (1-ahead prefetch)
    {
        float4 cw = cand[0];
#pragma unroll 1
        for (int i = 0; i < KNB; ++i) {
            float4 nxt = cand[i + 1];                // i+1 <= 20 < SEGW: safe
            float cv = dist(cw);
#pragma unroll
            for (int j = 0; j < KNB; ++j) {
                float nv = fmaxf(cv, vals[j]);
                cv       = fminf(cv, vals[j]);
                vals[j]  = nv;
            }
            cw = nxt;
        }
    }
    float vmin = vals[KNB - 1];
    float thr  = vmin;
    int   cnt  = 0;

    // (R16-J + R18) publish {v20,v10,v5,v3}; tighten thr with union bounds.
    // racy by design: stale stats are older (smaller) -> still <= t.
    auto refresh = [&]() {
        shareV[wv][lane] = make_float4(vmin, vals[9], vals[4], vals[2]);
        float4 s0 = shareV[0][lane], s1 = shareV[1][lane];
        float4 s2 = shareV[2][lane], s3 = shareV[3][lane];
        float4 s4 = shareV[4][lane], s5 = shareV[5][lane];
        float4 s6 = shareV[6][lane], s7 = shareV[7][lane];
        // 20 elems >= max of per-wave 20ths
        float m19 = fmaxf(fmaxf(fmaxf(s0.x, s1.x), fmaxf(s2.x, s3.x)),
                          fmaxf(fmaxf(s4.x, s5.x), fmaxf(s6.x, s7.x)));
        // pair bound: 2 waves x 10 elems >= min(v10 pair)
        float b9 = fmaxf(fmaxf(fminf(s0.y, s1.y), fminf(s2.y, s3.y)),
                         fmaxf(fminf(s4.y, s5.y), fminf(s6.y, s7.y)));
        // quad bound: 4 waves x 5 elems >= min(v5 quad)
        float q0 = fminf(fminf(s0.z, s1.z), fminf(s2.z, s3.z));
        float q1 = fminf(fminf(s4.z, s5.z), fminf(s6.z, s7.z));
        float b4 = fmaxf(q0, q1);
        // octet bound: 8 waves x 3 elems >= min of all v3 (24 >= 20)
        float b3 = fminf(fminf(fminf(s0.w, s1.w), fminf(s2.w, s3.w)),
                         fminf(fminf(s4.w, s5.w), fminf(s6.w, s7.w)));
        thr = fmaxf(fmaxf(fmaxf(thr, m19), fmaxf(b9, b4)), b3);
    };
    refresh();                                       // early seed (lists full)

    auto flush = [&]() {
        float cv = sm.buf[0][tid];                   // speculative 1-ahead
#pragma unroll
        for (int j = 0; j < NSLOT; ++j) {
            if (!__any(j < cnt)) break;
            float nxt = (j + 1 < NSLOT) ? sm.buf[j + 1][tid] : -INFINITY;
            float c = (j < cnt) ? cv : -INFINITY;
            if (__any(c > vals[KNB - 1])) {          // (R16-K) stale-slot skip
#pragma unroll
                for (int q = 0; q < KNB; ++q) {      // 2-op step: max/min
                    float nv = fmaxf(c, vals[q]);
                    c        = fminf(c, vals[q]);
                    vals[q]  = nv;
                }
            }
            cv = nxt;
        }
        vmin = vals[KNB - 1];
        cnt = 0;
        thr = fmaxf(thr, vmin);
    };

    // remainder of first 64-cand chunk, buffered (<=12 resident + 4 = 16)
    {
        float4 c4[4];
#pragma unroll
        for (int u = 0; u < 4; ++u) c4[u] = cand[KNB + u];
#pragma unroll 1
        for (int i = KNB; i < 64; i += 4) {
            float4 n4[4];
            const int nx = (i + 4 < 64) ? i + 4 : KNB;   // clamp: safe reload
#pragma unroll
            for (int u = 0; u < 4; ++u) n4[u] = cand[nx + u];
            if ((i & 15) == 4) refresh();            // i = 36, 52 (early flood)
#pragma unroll
            for (int u = 0; u < 4; ++u) {
                float d = dist(c4[u]);
                if (d > thr) { sm.buf[cnt][tid] = d; ++cnt; }
            }
            if (__any(cnt >= 13)) flush();
#pragma unroll
            for (int u = 0; u < 4; ++u) c4[u] = n4[u];
        }
    }
    flush();                                         // leave cnt=0 for main

    // main scan: threshold refresh every 32, flush check every 8,
    // ping-pong 8-wide candidate prefetch across the backedge
    {
        float4 ca[8], cb[8];
#pragma unroll
        for (int u = 0; u < 8; ++u) ca[u] = cand[64 + u];
#pragma unroll 1
        for (int i = 64; i < SEGW; i += 16) {
#pragma unroll
            for (int u = 0; u < 8; ++u) cb[u] = cand[i + 8 + u];
            if ((i & 31) == 0) refresh();
#pragma unroll
            for (int u = 0; u < 8; ++u) {
                float d = dist(ca[u]);
                if (d > thr) { sm.buf[cnt][tid] = d; ++cnt; }
            }
            if (__any(cnt >= 9)) flush();            // <=8 resident + 8 = 16
            const int nx = (i + 16 < SEGW) ? i + 16 : 64;  // clamp: safe
#pragma unroll
            for (int u = 0; u < 8; ++u) ca[u] = cand[nx + u];
#pragma unroll
            for (int u = 0; u < 8; ++u) {
                float d = dist(cb[u]);
                if (d > thr) { sm.buf[cnt][tid] = d; ++cnt; }
            }
            if (__any(cnt >= 9)) flush();
        }
    }
    flush();
    __syncthreads();                                 // retire push buffers

#pragma unroll
    for (int j = 0; j < KNB; ++j) sm.vals[wv][j][lane] = vals[j];
    __syncthreads();

    // every wave redundantly merges the 8 sorted value lists -> t (20th)
    float t = -INFINITY;
    {
        int p0 = 0, p1 = 0, p2 = 0, p3 = 0, p4 = 0, p5 = 0, p6 = 0, p7 = 0;
#pragma unroll 1
        for (int k = 0; k < KNB; ++k) {
            float e0 = sm.vals[0][p0][lane], e1 = sm.vals[1][p1][lane];
            float e2 = sm.vals[2][p2][lane], e3 = sm.vals[3][p3][lane];
            float e4 = sm.vals[4][p4][lane], e5 = sm.vals[5][p5][lane];
            float e6 = sm.vals[6][p6][lane], e7 = sm.vals[7][p7][lane];
            float bv = e0; int bs = 0;
            if (e1 > bv) { bv = e1; bs = 1; }
            if (e2 > bv) { bv = e2; bs = 2; }
            if (e3 > bv) { bv = e3; bs = 3; }
            if (e4 > bv) { bv = e4; bs = 4; }
            if (e5 > bv) { bv = e5; bs = 5; }
            if (e6 > bv) { bv = e6; bs = 6; }
            if (e7 > bv) { bv = e7; bs = 7; }
            t = bv;
            p0 += (bs == 0); p1 += (bs == 1); p2 += (bs == 2); p3 += (bs == 3);
            p4 += (bs == 4); p5 += (bs == 5); p6 += (bs == 6); p7 += (bs == 7);
        }
    }
    __syncthreads();                                 // retire vals (alias b)

    // phase B: collect survivors d >= t (idx | strict-bit), wave-uniform
    // streamed re-scan with ping-pong prefetch (R11-validated)
    int myc = 0;
    {
        float4 ca[8], cb[8];
#pragma unroll
        for (int u = 0; u < 8; ++u) ca[u] = cand[u];
#pragma unroll 1
        for (int i = 0; i < SEGW; i += 16) {
#pragma unroll
            for (int u = 0; u < 8; ++u) cb[u] = cand[i + 8 + u];
#pragma unroll
            for (int u = 0; u < 8; ++u) {
                float d = dist(ca[u]);
                if (d >= t) {
                    if (myc < KNB)
                        sm.b.list[wv][lane][myc] =
                            (wv * SEGW + i + u) | ((d > t) ? (int)0x80000000 : 0);
                    ++myc;
                }
            }
            const int nx = (i + 16 < SEGW) ? i + 16 : 0;   // clamp: safe
#pragma unroll
            for (int u = 0; u < 8; ++u) ca[u] = cand[nx + u];
#pragma unroll
            for (int u = 0; u < 8; ++u) {
                float d = dist(cb[u]);
                if (d >= t) {
                    if (myc < KNB)
                        sm.b.list[wv][lane][myc] =
                            (wv * SEGW + i + 8 + u) | ((d > t) ? (int)0x80000000 : 0);
                    ++myc;
                }
            }
        }
    }
    sm.b.cnt[wv][lane] = (myc < KNB) ? myc : KNB;
    __syncthreads();

    if (wv == 0) {
        int nout = 0;
#pragma unroll 1
        for (int pass = 0; pass < 2; ++pass) {       // 0: d>t, 1: d==t
#pragma unroll 1
            for (int w = 0; w < NSEG; ++w) {
                int cw = sm.b.cnt[w][lane];
#pragma unroll 1
                for (int j = 0; j < KNB; ++j) {
                    if (!__any(j < cw)) break;
                    if (j < cw) {
                        int e = sm.b.list[w][lane][j];
                        bool strict = (e < 0);
                        bool take = (pass == 0) ? strict : !strict;
                        if (take && nout < KNB) {
                            outk[nout][lane] = e & 0x7fffffff;
                            ++nout;
                        }
                    }
                }
            }
        }
    }
    __syncthreads();                                 // outk ready; b dead

    // ------------------- fused conv epilogue (R9-validated) -----------------
#pragma unroll
    for (int r = 0; r < 3; ++r) {
        int p = tid + r * 512;
        if (p < KNB * 64) {
            int k = p >> 6, pt = p & 63;
            int nb = outk[k][pt];
            float4 nq = xp[(b << 12) + nb];              // scattered (spread)
            float4 cq = xp[g0 + pt];                     // L1-hot
            sm.f.dif[k][0][pt] = __fsub_rn(nq.x, cq.x);
            sm.f.dif[k][1][pt] = __fsub_rn(nq.y, cq.y);
            sm.f.dif[k][2][pt] = __fsub_rn(nq.z, cq.z);
        }
    }
    __syncthreads();

    float dx[KNB], dy[KNB], dz[KNB];
#pragma unroll
    for (int k = 0; k < KNB; ++k) {                      // conflict-free LDS
        dx[k] = sm.f.dif[k][0][lane];
        dy[k] = sm.f.dif[k][1][lane];
        dz[k] = sm.f.dif[k][2][lane];
    }

    // conv1 eighth: channels [8*wv, 8*wv+8)
    const float4* w1fv = (const float4*)w1f;
#pragma unroll 1
    for (int cc = 0; cc < 8; ++cc) {
        int c = wv * 8 + cc;                             // uniform -> s_load
        float4 wa = w1fv[c * 2];                         // {W0,W1,W2,W3}
        float4 wb = w1fv[c * 2 + 1];                     // {W4,W5,B1',pad}
        float base = wb.z + wa.w * cx + wb.x * cy + wb.y * cz;
        float m1 = -INFINITY, s = 0.f;
#pragma unroll
        for (int k = 0; k < KNB; ++k) {
            float h = fmaf(dz[k], wa.z, fmaf(dy[k], wa.y, fmaf(dx[k], wa.x, base)));
            float r = fmaxf(0.f, h);
            m1 = fmaxf(m1, r);
            s += r;
        }
        sm.f.cat[c * 64 + lane]        = m1;
        sm.f.cat[(64 + c) * 64 + lane] = s / 20.0f;
    }
    __syncthreads();

    const size_t SEC = (size_t)NB * 64 * NPB;   // elements per output section

    // write m1/m2 rows straight from cat (coalesced 256B rows)
#pragma unroll 1
    for (int q = 0; q < 16; ++q) {
        int r  = wv * 16 + q;                   // 0..127, uniform
        int ch = r & 63;
        float* dst = out + SEC * (1 + (r >> 6)) + ((size_t)b * 64 + ch) * NPB + n0;
        dst[lane] = sm.f.cat[r * 64 + lane];
    }

    // conv2 eighth: outputs [8*wv, 8*wv+8)
    const int ob = wv * 8;                      // uniform -> s_load weights
    float acc[8];
#pragma unroll
    for (int j = 0; j < 8; ++j) acc[j] = w2b[ob + j];
#pragma unroll 4
    for (int c = 0; c < 128; ++c) {
        float v = sm.f.cat[c * 64 + lane];
        const float4* wr = (const float4*)(w2f + c * 64 + ob);
        float4 q0 = wr[0], q1 = wr[1];
        acc[0] = fmaf(v, q0.x, acc[0]);  acc[1] = fmaf(v, q0.y, acc[1]);
        acc[2] = fmaf(v, q0.z, acc[2]);  acc[3] = fmaf(v, q0.w, acc[3]);
        acc[4] = fmaf(v, q1.x, acc[4]);  acc[5] = fmaf(v, q1.y, acc[5]);
        acc[6] = fmaf(v, q1.z, acc[6]);  acc[7] = fmaf(v, q1.w, acc[7]);
    }
#pragma unroll
    for (int j = 0; j < 8; ++j) acc[j] = fmaxf(0.f, acc[j]);

    __syncthreads();                            // all waves done reading cat
#pragma unroll
    for (int j = 0; j < 8; ++j) sm.f.cat[(ob + j) * 64 + lane] = acc[j];
    __syncthreads();
#pragma unroll 1
    for (int q = 0; q < 8; ++q) {
        int oo = wv * 8 + q;
        out[((size_t)b * 64 + oo) * NPB + n0 + lane] = sm.f.cat[oo * 64 + lane];
    }
}

extern "C" void kernel_launch(void* const* d_in, const int* in_sizes, int n_in,
                              void* d_out, int out_size, void* d_ws, size_t ws_size,
                              hipStream_t stream) {
    const float* x   = (const float*)d_in[0];
    const float* w1  = (const float*)d_in[1];
    const float* b1  = (const float*)d_in[2];
    const float* g1  = (const float*)d_in[3];
    const float* be1 = (const float*)d_in[4];
    const float* rm1 = (const float*)d_in[5];
    const float* rv1 = (const float*)d_in[6];
    const float* w2  = (const float*)d_in[7];
    const float* b2  = (const float*)d_in[8];
    const float* g2  = (const float*)d_in[9];
    const float* be2 = (const float*)d_in[10];
    const float* rm2 = (const float*)d_in[11];
    const float* rv2 = (const float*)d_in[12];

    char*   ws  = (char*)d_ws;
    float4* xp  = (float4*)ws;                      // 512 KB
    float*  w1f = (float*)(ws + 512 * 1024);        // 2 KB
    float*  w2f = w1f + 64 * 8;                     // 32 KB
    float*  w2b = w2f + 64 * 128;                   // 256 B

    pack_prep_kernel<<<NPTS / 256, 256, 0, stream>>>(
        x, xp, w1, b1, g1, be1, rm1, rv1, w2, b2, g2, be2, rm2, rv2,
        w1f, w2f, w2b);
    knnfuse_kernel<<<NPTS / 64, 512, 0, stream>>>(xp, w1f, w2f, w2b,
                                                  (float*)d_out);
}

// Round 10
// 232.607 us; speedup vs baseline: 3.0723x; 1.0208x over previous
//
#include <hip/hip_runtime.h>
#include <cstddef>

#define NPB  4096            // points per batch
#define KNB  20              // neighbors
#define NB   8               // batches
#define NPTS (NB * NPB)      // 32768 total points
#define NSEG 8               // segment-waves per block
#define SEGW 512             // candidates per segment
#define NSLOT 16             // push-buffer slots per thread
#define MG   1e-3f           // fast-vs-exact dist margin (|err| <= ~1e-4)

// ---------------------------------------------------------------------------
// Kernel A+P (R15-validated): pack (x,y,z,xx) float4 + BN fold, w2f fold
// spread over 16 blocks with coalesced reads / scattered writes.
// ---------------------------------------------------------------------------
__global__ __launch_bounds__(256) void pack_prep_kernel(
    const float* __restrict__ x, float4* __restrict__ xp,
    const float* __restrict__ w1, const float* __restrict__ b1,
    const float* __restrict__ g1, const float* __restrict__ be1,
    const float* __restrict__ rm1, const float* __restrict__ rv1,
    const float* __restrict__ w2, const float* __restrict__ b2,
    const float* __restrict__ g2, const float* __restrict__ be2,
    const float* __restrict__ rm2, const float* __restrict__ rv2,
    float* __restrict__ w1f, float* __restrict__ w2f, float* __restrict__ w2b)
{
    const int tid = threadIdx.x;
    const int g = blockIdx.x * 256 + tid;
    const int b = g >> 12, n = g & (NPB - 1);
    const float* xb = x + (size_t)b * 3 * NPB;
    float a0 = xb[n], a1 = xb[NPB + n], a2 = xb[2 * NPB + n];
    float xx = __fadd_rn(__fadd_rn(__fmul_rn(a0, a0), __fmul_rn(a1, a1)),
                         __fmul_rn(a2, a2));
    xp[g] = make_float4(a0, a1, a2, xx);

    if (blockIdx.x == 0 && tid < 64) {
        float sc1 = g1[tid] * rsqrtf(rv1[tid] + 1e-5f);
        float sh1 = be1[tid] - rm1[tid] * sc1;
#pragma unroll
        for (int j = 0; j < 6; ++j) w1f[tid * 8 + j] = sc1 * w1[tid * 6 + j];
        w1f[tid * 8 + 6] = sc1 * b1[tid] + sh1;
        w1f[tid * 8 + 7] = 0.f;
        float sc2 = g2[tid] * rsqrtf(rv2[tid] + 1e-5f);
        w2b[tid] = sc2 * b2[tid] + (be2[tid] - rm2[tid] * sc2);
    }
    if (blockIdx.x < 16) {
#pragma unroll
        for (int r = 0; r < 2; ++r) {
            int j = blockIdx.x * 512 + r * 256 + tid;   // linear index into w2
            int o = j >> 7, c = j & 127;                // w2[o][c]
            float sc2 = g2[o] * rsqrtf(rv2[o] + 1e-5f);
            w2f[c * 64 + o] = sc2 * w2[j];
        }
    }
}

// ---------------------------------------------------------------------------
// Kernel B+C merged. R19 = R18 + fast-screen scan:
//  - scan gate uses 4-op fma dist (dfast) vs (thr - MG); conservative since
//    |dfast - dexact| <= ~1e-4 << MG, so nothing with dexact > thr is missed.
//  - push buffer holds {dfast, idx}; flush gathers cand[idx] (L1, 8 KB
//    window) and inserts the EXACT 8-op reference-rounded dist -> the vals
//    lists, t, phase B, and selection are bit-identical to R11/R18.
//  - (K) stale-slot skip now screens on dfast with the same margin.
// Phase B and warm-up keep exact dist. R16-J/R18 threshold bounds unchanged.
// ---------------------------------------------------------------------------
union KSMem {
    int2 pbuf[NSLOT][512];          // 64 KB scan push pairs {dfast_bits, idx}
    float vals[NSEG][KNB][64];      // 40 KB sorted partial lists [wave][j][pt]
    struct {
        int list[NSEG][64][21];     // 42 KB survivors idx|(strict<<31)
        int cnt[NSEG][64];          //  2 KB
    } b;                            // 44 KB
    struct {
        float cat[128 * 64];        // 32 KB [c][pt]: c<64 m1, c>=64 m2
        float dif[KNB][3][64];      // 15 KB [k][coord][pt]
    } f;                            // 47 KB  (union = 64 KB)
};

__global__ __launch_bounds__(512, 4) void knnfuse_kernel(
    const float4* __restrict__ xp,
    const float* __restrict__ w1f, const float* __restrict__ w2f,
    const float* __restrict__ w2b, float* __restrict__ out)
{
    __shared__ KSMem sm;
    __shared__ float4 shareV[NSEG][64]; // 8 KB {v20, v10, v5, v3} per wave/pt
    __shared__ int   outk[KNB][64];     // 5 KB final neighbor idx [k][pt]

    const int tid  = threadIdx.x;
    const int wv   = __builtin_amdgcn_readfirstlane(tid >> 6);
    const int lane = tid & 63;
    const int g0   = blockIdx.x * 64;
    const int b    = g0 >> 12;
    const int n0   = g0 & (NPB - 1);

    shareV[wv][lane] = make_float4(-INFINITY, -INFINITY, -INFINITY, -INFINITY);
    __syncthreads();

    const float4 me = xp[g0 + lane];                 // coalesced
    const float cx = me.x, cy = me.y, cz = me.z, xxn = me.w;
    const float cx2 = 2.0f * cx, cy2 = 2.0f * cy, cz2 = 2.0f * cz;
    const float nxx = -xxn;

    // exact reference-rounded dist (selection-critical path)
    auto dist = [&](float4 q) -> float {
        float inner = __fadd_rn(__fadd_rn(__fmul_rn(cx, q.x), __fmul_rn(cy, q.y)),
                                __fmul_rn(cz, q.z));
        return __fsub_rn(__fsub_rn(__fmul_rn(2.0f, inner), xxn), q.w);
    };
    // fast 4-op screen: |dfast - dist| <= ~1e-4 (values bounded ~160)
    auto dfast = [&](float4 q) -> float {
        return fmaf(cx2, q.x, fmaf(cy2, q.y, fmaf(cz2, q.z,
                    __fsub_rn(nxx, q.w))));
    };

    float vals[KNB];
#pragma unroll
    for (int j = 0; j < KNB; ++j) vals[j] = -INFINITY;

    const float4* cand = xp + (b << 12) + wv * SEGW; // wave-uniform -> s_load

    // warm-up: direct sorted insert of first 20 candidates, EXACT dist
    {
        float4 cw = cand[0];
#pragma unroll 1
        for (int i = 0; i < KNB; ++i) {
            float4 nxt = cand[i + 1];                // i+1 <= 20 < SEGW: safe
            float cv = dist(cw);
#pragma unroll
            for (int j = 0; j < KNB; ++j) {
                float nv = fmaxf(cv, vals[j]);
                cv       = fminf(cv, vals[j]);
                vals[j]  = nv;
            }
            cw = nxt;
        }
    }
    float vmin = vals[KNB - 1];
    float thr  = vmin;
    float thrm = thr - MG;                           // screened gate
    int   cnt  = 0;

    // (R16-J + R18) publish {v20,v10,v5,v3}; tighten thr with union bounds.
    // racy by design: stale stats are older (smaller) -> still <= t.
    auto refresh = [&]() {
        shareV[wv][lane] = make_float4(vmin, vals[9], vals[4], vals[2]);
        float4 s0 = shareV[0][lane], s1 = shareV[1][lane];
        float4 s2 = shareV[2][lane], s3 = shareV[3][lane];
        float4 s4 = shareV[4][lane], s5 = shareV[5][lane];
        float4 s6 = shareV[6][lane], s7 = shareV[7][lane];
        float m19 = fmaxf(fmaxf(fmaxf(s0.x, s1.x), fmaxf(s2.x, s3.x)),
                          fmaxf(fmaxf(s4.x, s5.x), fmaxf(s6.x, s7.x)));
        float b9 = fmaxf(fmaxf(fminf(s0.y, s1.y), fminf(s2.y, s3.y)),
                         fmaxf(fminf(s4.y, s5.y), fminf(s6.y, s7.y)));
        float q0 = fminf(fminf(s0.z, s1.z), fminf(s2.z, s3.z));
        float q1 = fminf(fminf(s4.z, s5.z), fminf(s6.z, s7.z));
        float b4 = fmaxf(q0, q1);
        float b3 = fminf(fminf(fminf(s0.w, s1.w), fminf(s2.w, s3.w)),
                         fminf(fminf(s4.w, s5.w), fminf(s6.w, s7.w)));
        thr = fmaxf(fmaxf(fmaxf(thr, m19), fmaxf(b9, b4)), b3);
        thrm = thr - MG;
    };
    refresh();                                       // early seed (lists full)

    // flush: gather cand[idx] (L1, 8 KB window), insert EXACT dist.
    auto flush = [&]() {
        int2   cp = sm.pbuf[0][tid];                 // speculative 1-ahead
        float4 cq = cand[cp.y & (SEGW - 1)];         // sanitized spec gather
#pragma unroll
        for (int j = 0; j < NSLOT; ++j) {
            if (!__any(j < cnt)) break;
            int2 np = (j + 1 < NSLOT) ? sm.pbuf[j + 1][tid] : make_int2(0, 0);
            float4 nq = cand[np.y & (SEGW - 1)];     // prefetch next gather
            float cf = (j < cnt) ? __int_as_float(cp.x) : -INFINITY;
            if (__any(cf > vals[KNB - 1] - MG)) {    // (K) screened skip
                float c = (j < cnt) ? dist(cq) : -INFINITY;  // exact 8-op
#pragma unroll
                for (int q = 0; q < KNB; ++q) {      // 2-op step: max/min
                    float nv = fmaxf(c, vals[q]);
                    c        = fminf(c, vals[q]);
                    vals[q]  = nv;
                }
            }
            cp = np; cq = nq;
        }
        vmin = vals[KNB - 1];
        cnt = 0;
        thr = fmaxf(thr, vmin);
        thrm = thr - MG;
    };

    // remainder of first 64-cand chunk, buffered (<=12 resident + 4 = 16)
    {
        float4 c4[4];
#pragma unroll
        for (int u = 0; u < 4; ++u) c4[u] = cand[KNB + u];
#pragma unroll 1
        for (int i = KNB; i < 64; i += 4) {
            float4 n4[4];
            const int nx = (i + 4 < 64) ? i + 4 : KNB;   // clamp: safe reload
#pragma unroll
            for (int u = 0; u < 4; ++u) n4[u] = cand[nx + u];
            if ((i & 15) == 4) refresh();            // i = 36, 52 (early flood)
#pragma unroll
            for (int u = 0; u < 4; ++u) {
                float d = dfast(c4[u]);
                if (d > thrm) {
                    sm.pbuf[cnt][tid] = make_int2(__float_as_int(d), i + u);
                    ++cnt;
                }
            }
            if (__any(cnt >= 13)) flush();
#pragma unroll
            for (int u = 0; u < 4; ++u) c4[u] = n4[u];
        }
    }
    flush();                                         // leave cnt=0 for main

    // main scan: threshold refresh every 32, flush check every 8,
    // ping-pong 8-wide candidate prefetch across the backedge
    {
        float4 ca[8], cb[8];
#pragma unroll
        for (int u = 0; u < 8; ++u) ca[u] = cand[64 + u];
#pragma unroll 1
        for (int i = 64; i < SEGW; i += 16) {
#pragma unroll
            for (int u = 0; u < 8; ++u) cb[u] = cand[i + 8 + u];
            if ((i & 31) == 0) refresh();
#pragma unroll
            for (int u = 0; u < 8; ++u) {
                float d = dfast(ca[u]);
                if (d > thrm) {
                    sm.pbuf[cnt][tid] = make_int2(__float_as_int(d), i + u);
                    ++cnt;
                }
            }
            if (__any(cnt >= 9)) flush();            // <=8 resident + 8 = 16
            const int nx = (i + 16 < SEGW) ? i + 16 : 64;  // clamp: safe
#pragma unroll
            for (int u = 0; u < 8; ++u) ca[u] = cand[nx + u];
#pragma unroll
            for (int u = 0; u < 8; ++u) {
                float d = dfast(cb[u]);
                if (d > thrm) {
                    sm.pbuf[cnt][tid] = make_int2(__float_as_int(d), i + 8 + u);
                    ++cnt;
                }
            }
            if (__any(cnt >= 9)) flush();
        }
    }
    flush();
    __syncthreads();                                 // retire push buffers

#pragma unroll
    for (int j = 0; j < KNB; ++j) sm.vals[wv][j][lane] = vals[j];
    __syncthreads();

    // every wave redundantly merges the 8 sorted value lists -> t (20th)
    float t = -INFINITY;
    {
        int p0 = 0, p1 = 0, p2 = 0, p3 = 0, p4 = 0, p5 = 0, p6 = 0, p7 = 0;
#pragma unroll 1
        for (int k = 0; k < KNB; ++k) {
            float e0 = sm.vals[0][p0][lane], e1 = sm.vals[1][p1][lane];
            float e2 = sm.vals[2][p2][lane], e3 = sm.vals[3][p3][lane];
            float e4 = sm.vals[4][p4][lane], e5 = sm.vals[5][p5][lane];
            float e6 = sm.vals[6][p6][lane], e7 = sm.vals[7][p7][lane];
            float bv = e0; int bs = 0;
            if (e1 > bv) { bv = e1; bs = 1; }
            if (e2 > bv) { bv = e2; bs = 2; }
            if (e3 > bv) { bv = e3; bs = 3; }
            if (e4 > bv) { bv = e4; bs = 4; }
            if (e5 > bv) { bv = e5; bs = 5; }
            if (e6 > bv) { bv = e6; bs = 6; }
            if (e7 > bv) { bv = e7; bs = 7; }
            t = bv;
            p0 += (bs == 0); p1 += (bs == 1); p2 += (bs == 2); p3 += (bs == 3);
            p4 += (bs == 4); p5 += (bs == 5); p6 += (bs == 6); p7 += (bs == 7);
        }
    }
    __syncthreads();                                 // retire vals (alias b)

    // phase B: collect survivors d >= t (idx | strict-bit), wave-uniform
    // streamed re-scan with ping-pong prefetch, EXACT dist (R11-validated)
    int myc = 0;
    {
        float4 ca[8], cb[8];
#pragma unroll
        for (int u = 0; u < 8; ++u) ca[u] = cand[u];
#pragma unroll 1
        for (int i = 0; i < SEGW; i += 16) {
#pragma unroll
            for (int u = 0; u < 8; ++u) cb[u] = cand[i + 8 + u];
#pragma unroll
            for (int u = 0; u < 8; ++u) {
                float d = dist(ca[u]);
                if (d >= t) {
                    if (myc < KNB)
                        sm.b.list[wv][lane][myc] =
                            (wv * SEGW + i + u) | ((d > t) ? (int)0x80000000 : 0);
                    ++myc;
                }
            }
            const int nx = (i + 16 < SEGW) ? i + 16 : 0;   // clamp: safe
#pragma unroll
            for (int u = 0; u < 8; ++u) ca[u] = cand[nx + u];
#pragma unroll
            for (int u = 0; u < 8; ++u) {
                float d = dist(cb[u]);
                if (d >= t) {
                    if (myc < KNB)
                        sm.b.list[wv][lane][myc] =
                            (wv * SEGW + i + 8 + u) | ((d > t) ? (int)0x80000000 : 0);
                    ++myc;
                }
            }
        }
    }
    sm.b.cnt[wv][lane] = (myc < KNB) ? myc : KNB;
    __syncthreads();

    if (wv == 0) {
        int nout = 0;
#pragma unroll 1
        for (int pass = 0; pass < 2; ++pass) {       // 0: d>t, 1: d==t
#pragma unroll 1
            for (int w = 0; w < NSEG; ++w) {
                int cw = sm.b.cnt[w][lane];
#pragma unroll 1
                for (int j = 0; j < KNB; ++j) {
                    if (!__any(j < cw)) break;
                    if (j < cw) {
                        int e = sm.b.list[w][lane][j];
                        bool strict = (e < 0);
                        bool take = (pass == 0) ? strict : !strict;
                        if (take && nout < KNB) {
                            outk[nout][lane] = e & 0x7fffffff;
                            ++nout;
                        }
                    }
                }
            }
        }
    }
    __syncthreads();                                 // outk ready; b dead

    // ------------------- fused conv epilogue (R9-validated) -----------------
#pragma unroll
    for (int r = 0; r < 3; ++r) {
        int p = tid + r * 512;
        if (p < KNB * 64) {
            int k = p >> 6, pt = p & 63;
            int nb = outk[k][pt];
            float4 nq = xp[(b << 12) + nb];              // scattered (spread)
            float4 cq = xp[g0 + pt];                     // L1-hot
            sm.f.dif[k][0][pt] = __fsub_rn(nq.x, cq.x);
            sm.f.dif[k][1][pt] = __fsub_rn(nq.y, cq.y);
            sm.f.dif[k][2][pt] = __fsub_rn(nq.z, cq.z);
        }
    }
    __syncthreads();

    float dx[KNB], dy[KNB], dz[KNB];
#pragma unroll
    for (int k = 0; k < KNB; ++k) {                      // conflict-free LDS
        dx[k] = sm.f.dif[k][0][lane];
        dy[k] = sm.f.dif[k][1][lane];
        dz[k] = sm.f.dif[k][2][lane];
    }

    // conv1 eighth: channels [8*wv, 8*wv+8)
    const float4* w1fv = (const float4*)w1f;
#pragma unroll 1
    for (int cc = 0; cc < 8; ++cc) {
        int c = wv * 8 + cc;                             // uniform -> s_load
        float4 wa = w1fv[c * 2];                         // {W0,W1,W2,W3}
        float4 wb = w1fv[c * 2 + 1];                     // {W4,W5,B1',pad}
        float base = wb.z + wa.w * cx + wb.x * cy + wb.y * cz;
        float m1 = -INFINITY, s = 0.f;
#pragma unroll
        for (int k = 0; k < KNB; ++k) {
            float h = fmaf(dz[k], wa.z, fmaf(dy[k], wa.y, fmaf(dx[k], wa.x, base)));
            float r = fmaxf(0.f, h);
            m1 = fmaxf(m1, r);
            s += r;
        }
        sm.f.cat[c * 64 + lane]        = m1;
        sm.f.cat[(64 + c) * 64 + lane] = s / 20.0f;
    }
    __syncthreads();

    const size_t SEC = (size_t)NB * 64 * NPB;   // elements per output section

    // write m1/m2 rows straight from cat (coalesced 256B rows)
#pragma unroll 1
    for (int q = 0; q < 16; ++q) {
        int r  = wv * 16 + q;                   // 0..127, uniform
        int ch = r & 63;
        float* dst = out + SEC * (1 + (r >> 6)) + ((size_t)b * 64 + ch) * NPB + n0;
        dst[lane] = sm.f.cat[r * 64 + lane];
    }

    // conv2 eighth: outputs [8*wv, 8*wv+8)
    const int ob = wv * 8;                      // uniform -> s_load weights
    float acc[8];
#pragma unroll
    for (int j = 0; j < 8; ++j) acc[j] = w2b[ob + j];
#pragma unroll 4
    for (int c = 0; c < 128; ++c) {
        float v = sm.f.cat[c * 64 + lane];
        const float4* wr = (const float4*)(w2f + c * 64 + ob);
        float4 q0 = wr[0], q1 = wr[1];
        acc[0] = fmaf(v, q0.x, acc[0]);  acc[1] = fmaf(v, q0.y, acc[1]);
        acc[2] = fmaf(v, q0.z, acc[2]);  acc[3] = fmaf(v, q0.w, acc[3]);
        acc[4] = fmaf(v, q1.x, acc[4]);  acc[5] = fmaf(v, q1.y, acc[5]);
        acc[6] = fmaf(v, q1.z, acc[6]);  acc[7] = fmaf(v, q1.w, acc[7]);
    }
#pragma unroll
    for (int j = 0; j < 8; ++j) acc[j] = fmaxf(0.f, acc[j]);

    __syncthreads();                            // all waves done reading cat
#pragma unroll
    for (int j = 0; j < 8; ++j) sm.f.cat[(ob + j) * 64 + lane] = acc[j];
    __syncthreads();
#pragma unroll 1
    for (int q = 0; q < 8; ++q) {
        int oo = wv * 8 + q;
        out[((size_t)b * 64 + oo) * NPB + n0 + lane] = sm.f.cat[oo * 64 + lane];
    }
}

extern "C" void kernel_launch(void* const* d_in, const int* in_sizes, int n_in,
                              void* d_out, int out_size, void* d_ws, size_t ws_size,
                              hipStream_t stream) {
    const float* x   = (const float*)d_in[0];
    const float* w1  = (const float*)d_in[1];
    const float* b1  = (const float*)d_in[2];
    const float* g1  = (const float*)d_in[3];
    const float* be1 = (const float*)d_in[4];
    const float* rm1 = (const float*)d_in[5];
    const float* rv1 = (const float*)d_in[6];
    const float* w2  = (const float*)d_in[7];
    const float* b2  = (const float*)d_in[8];
    const float* g2  = (const float*)d_in[9];
    const float* be2 = (const float*)d_in[10];
    const float* rm2 = (const float*)d_in[11];
    const float* rv2 = (const float*)d_in[12];

    char*   ws  = (char*)d_ws;
    float4* xp  = (float4*)ws;                      // 512 KB
    float*  w1f = (float*)(ws + 512 * 1024);        // 2 KB
    float*  w2f = w1f + 64 * 8;                     // 32 KB
    float*  w2b = w2f + 64 * 128;                   // 256 B

    pack_prep_kernel<<<NPTS / 256, 256, 0, stream>>>(
        x, xp, w1, b1, g1, be1, rm1, rv1, w2, b2, g2, be2, rm2, rv2,
        w1f, w2f, w2b);
    knnfuse_kernel<<<NPTS / 64, 512, 0, stream>>>(xp, w1f, w2f, w2b,
                                                  (float*)d_out);
}

// Round 11
// 228.358 us; speedup vs baseline: 3.1295x; 1.0186x over previous
//
#include <hip/hip_runtime.h>
#include <cstddef>

#define NPB  4096            // points per batch
#define KNB  20              // neighbors
#define NB   8               // batches
#define NPTS (NB * NPB)      // 32768 total points
#define NSEG 8               // segment-waves per block
#define SEGW 512             // candidates per segment
#define NSLOT 16             // push-buffer slots per thread
#define MG   1e-3f           // fast-vs-exact dist margin (|err| <= ~1e-4)

// ---------------------------------------------------------------------------
// Kernel A+P (R15-validated): pack (x,y,z,xx) float4 + BN fold, w2f fold
// spread over 16 blocks with coalesced reads / scattered writes.
// ---------------------------------------------------------------------------
__global__ __launch_bounds__(256) void pack_prep_kernel(
    const float* __restrict__ x, float4* __restrict__ xp,
    const float* __restrict__ w1, const float* __restrict__ b1,
    const float* __restrict__ g1, const float* __restrict__ be1,
    const float* __restrict__ rm1, const float* __restrict__ rv1,
    const float* __restrict__ w2, const float* __restrict__ b2,
    const float* __restrict__ g2, const float* __restrict__ be2,
    const float* __restrict__ rm2, const float* __restrict__ rv2,
    float* __restrict__ w1f, float* __restrict__ w2f, float* __restrict__ w2b)
{
    const int tid = threadIdx.x;
    const int g = blockIdx.x * 256 + tid;
    const int b = g >> 12, n = g & (NPB - 1);
    const float* xb = x + (size_t)b * 3 * NPB;
    float a0 = xb[n], a1 = xb[NPB + n], a2 = xb[2 * NPB + n];
    float xx = __fadd_rn(__fadd_rn(__fmul_rn(a0, a0), __fmul_rn(a1, a1)),
                         __fmul_rn(a2, a2));
    xp[g] = make_float4(a0, a1, a2, xx);

    if (blockIdx.x == 0 && tid < 64) {
        float sc1 = g1[tid] * rsqrtf(rv1[tid] + 1e-5f);
        float sh1 = be1[tid] - rm1[tid] * sc1;
#pragma unroll
        for (int j = 0; j < 6; ++j) w1f[tid * 8 + j] = sc1 * w1[tid * 6 + j];
        w1f[tid * 8 + 6] = sc1 * b1[tid] + sh1;
        w1f[tid * 8 + 7] = 0.f;
        float sc2 = g2[tid] * rsqrtf(rv2[tid] + 1e-5f);
        w2b[tid] = sc2 * b2[tid] + (be2[tid] - rm2[tid] * sc2);
    }
    if (blockIdx.x < 16) {
#pragma unroll
        for (int r = 0; r < 2; ++r) {
            int j = blockIdx.x * 512 + r * 256 + tid;   // linear index into w2
            int o = j >> 7, c = j & 127;                // w2[o][c]
            float sc2 = g2[o] * rsqrtf(rv2[o] + 1e-5f);
            w2f[c * 64 + o] = sc2 * w2[j];
        }
    }
}

// ---------------------------------------------------------------------------
// Kernel B+C merged. R20 = R19 + fast-screened phase B:
//  - phase B gate uses the 4-op dfast vs (t - MG); conservative (no exact
//    survivor d >= t can fail it, |dfast - dexact| <= ~1e-4 << MG).
//  - passers (~2.5/thread: 20 survivors spread over 8 segments) push u16
//    local idx into a small LDS buffer; flush-style processing gathers
//    cand[idx] (L1, 8 KB window) and applies the EXACT dist for the d >= t
//    filter and strict bit. Pushes are in ascending scan order -> appends
//    preserve the ascending-index invariant dedup requires. Survivor set,
//    order, and outputs bit-identical to R19/R11.
//  - scan side unchanged from R19 (fast-screen + exact-at-flush).
// ---------------------------------------------------------------------------
union KSMem {
    int2 pbuf[NSLOT][512];          // 64 KB scan push pairs {dfast_bits, idx}
    float vals[NSEG][KNB][64];      // 40 KB sorted partial lists [wave][j][pt]
    struct {
        int list[NSEG][64][21];     // 42 KB survivors idx|(strict<<31)
        int cnt[NSEG][64];          //  2 KB
        unsigned short pb2[NSLOT][512];  // 16 KB phase-B push idx (local)
    } b;                            // 60 KB
    struct {
        float cat[128 * 64];        // 32 KB [c][pt]: c<64 m1, c>=64 m2
        float dif[KNB][3][64];      // 15 KB [k][coord][pt]
    } f;                            // 47 KB  (union = 64 KB)
};

__global__ __launch_bounds__(512, 4) void knnfuse_kernel(
    const float4* __restrict__ xp,
    const float* __restrict__ w1f, const float* __restrict__ w2f,
    const float* __restrict__ w2b, float* __restrict__ out)
{
    __shared__ KSMem sm;
    __shared__ float4 shareV[NSEG][64]; // 8 KB {v20, v10, v5, v3} per wave/pt
    __shared__ int   outk[KNB][64];     // 5 KB final neighbor idx [k][pt]

    const int tid  = threadIdx.x;
    const int wv   = __builtin_amdgcn_readfirstlane(tid >> 6);
    const int lane = tid & 63;
    const int g0   = blockIdx.x * 64;
    const int b    = g0 >> 12;
    const int n0   = g0 & (NPB - 1);

    shareV[wv][lane] = make_float4(-INFINITY, -INFINITY, -INFINITY, -INFINITY);
    __syncthreads();

    const float4 me = xp[g0 + lane];                 // coalesced
    const float cx = me.x, cy = me.y, cz = me.z, xxn = me.w;
    const float cx2 = 2.0f * cx, cy2 = 2.0f * cy, cz2 = 2.0f * cz;
    const float nxx = -xxn;

    // exact reference-rounded dist (selection-critical path)
    auto dist = [&](float4 q) -> float {
        float inner = __fadd_rn(__fadd_rn(__fmul_rn(cx, q.x), __fmul_rn(cy, q.y)),
                                __fmul_rn(cz, q.z));
        return __fsub_rn(__fsub_rn(__fmul_rn(2.0f, inner), xxn), q.w);
    };
    // fast 4-op screen: |dfast - dist| <= ~1e-4 (values bounded ~200)
    auto dfast = [&](float4 q) -> float {
        return fmaf(cx2, q.x, fmaf(cy2, q.y, fmaf(cz2, q.z,
                    __fsub_rn(nxx, q.w))));
    };

    float vals[KNB];
#pragma unroll
    for (int j = 0; j < KNB; ++j) vals[j] = -INFINITY;

    const float4* cand = xp + (b << 12) + wv * SEGW; // wave-uniform -> s_load

    // warm-up: direct sorted insert of first 20 candidates, EXACT dist
    {
        float4 cw = cand[0];
#pragma unroll 1
        for (int i = 0; i < KNB; ++i) {
            float4 nxt = cand[i + 1];                // i+1 <= 20 < SEGW: safe
            float cv = dist(cw);
#pragma unroll
            for (int j = 0; j < KNB; ++j) {
                float nv = fmaxf(cv, vals[j]);
                cv       = fminf(cv, vals[j]);
                vals[j]  = nv;
            }
            cw = nxt;
        }
    }
    float vmin = vals[KNB - 1];
    float thr  = vmin;
    float thrm = thr - MG;                           // screened gate
    int   cnt  = 0;

    // (R16-J + R18) publish {v20,v10,v5,v3}; tighten thr with union bounds.
    // racy by design: stale stats are older (smaller) -> still <= t.
    auto refresh = [&]() {
        shareV[wv][lane] = make_float4(vmin, vals[9], vals[4], vals[2]);
        float4 s0 = shareV[0][lane], s1 = shareV[1][lane];
        float4 s2 = shareV[2][lane], s3 = shareV[3][lane];
        float4 s4 = shareV[4][lane], s5 = shareV[5][lane];
        float4 s6 = shareV[6][lane], s7 = shareV[7][lane];
        float m19 = fmaxf(fmaxf(fmaxf(s0.x, s1.x), fmaxf(s2.x, s3.x)),
                          fmaxf(fmaxf(s4.x, s5.x), fmaxf(s6.x, s7.x)));
        float b9 = fmaxf(fmaxf(fminf(s0.y, s1.y), fminf(s2.y, s3.y)),
                         fmaxf(fminf(s4.y, s5.y), fminf(s6.y, s7.y)));
        float q0 = fminf(fminf(s0.z, s1.z), fminf(s2.z, s3.z));
        float q1 = fminf(fminf(s4.z, s5.z), fminf(s6.z, s7.z));
        float b4 = fmaxf(q0, q1);
        float b3 = fminf(fminf(fminf(s0.w, s1.w), fminf(s2.w, s3.w)),
                         fminf(fminf(s4.w, s5.w), fminf(s6.w, s7.w)));
        thr = fmaxf(fmaxf(fmaxf(thr, m19), fmaxf(b9, b4)), b3);
        thrm = thr - MG;
    };
    refresh();                                       // early seed (lists full)

    // flush: gather cand[idx] (L1, 8 KB window), insert EXACT dist.
    auto flush = [&]() {
        int2   cp = sm.pbuf[0][tid];                 // speculative 1-ahead
        float4 cq = cand[cp.y & (SEGW - 1)];         // sanitized spec gather
#pragma unroll
        for (int j = 0; j < NSLOT; ++j) {
            if (!__any(j < cnt)) break;
            int2 np = (j + 1 < NSLOT) ? sm.pbuf[j + 1][tid] : make_int2(0, 0);
            float4 nq = cand[np.y & (SEGW - 1)];     // prefetch next gather
            float cf = (j < cnt) ? __int_as_float(cp.x) : -INFINITY;
            if (__any(cf > vals[KNB - 1] - MG)) {    // (K) screened skip
                float c = (j < cnt) ? dist(cq) : -INFINITY;  // exact 8-op
#pragma unroll
                for (int q = 0; q < KNB; ++q) {      // 2-op step: max/min
                    float nv = fmaxf(c, vals[q]);
                    c        = fminf(c, vals[q]);
                    vals[q]  = nv;
                }
            }
            cp = np; cq = nq;
        }
        vmin = vals[KNB - 1];
        cnt = 0;
        thr = fmaxf(thr, vmin);
        thrm = thr - MG;
    };

    // remainder of first 64-cand chunk, buffered (<=12 resident + 4 = 16)
    {
        float4 c4[4];
#pragma unroll
        for (int u = 0; u < 4; ++u) c4[u] = cand[KNB + u];
#pragma unroll 1
        for (int i = KNB; i < 64; i += 4) {
            float4 n4[4];
            const int nx = (i + 4 < 64) ? i + 4 : KNB;   // clamp: safe reload
#pragma unroll
            for (int u = 0; u < 4; ++u) n4[u] = cand[nx + u];
            if ((i & 15) == 4) refresh();            // i = 36, 52 (early flood)
#pragma unroll
            for (int u = 0; u < 4; ++u) {
                float d = dfast(c4[u]);
                if (d > thrm) {
                    sm.pbuf[cnt][tid] = make_int2(__float_as_int(d), i + u);
                    ++cnt;
                }
            }
            if (__any(cnt >= 13)) flush();
#pragma unroll
            for (int u = 0; u < 4; ++u) c4[u] = n4[u];
        }
    }
    flush();                                         // leave cnt=0 for main

    // main scan: threshold refresh every 32, flush check every 8,
    // ping-pong 8-wide candidate prefetch across the backedge
    {
        float4 ca[8], cb[8];
#pragma unroll
        for (int u = 0; u < 8; ++u) ca[u] = cand[64 + u];
#pragma unroll 1
        for (int i = 64; i < SEGW; i += 16) {
#pragma unroll
            for (int u = 0; u < 8; ++u) cb[u] = cand[i + 8 + u];
            if ((i & 31) == 0) refresh();
#pragma unroll
            for (int u = 0; u < 8; ++u) {
                float d = dfast(ca[u]);
                if (d > thrm) {
                    sm.pbuf[cnt][tid] = make_int2(__float_as_int(d), i + u);
                    ++cnt;
                }
            }
            if (__any(cnt >= 9)) flush();            // <=8 resident + 8 = 16
            const int nx = (i + 16 < SEGW) ? i + 16 : 64;  // clamp: safe
#pragma unroll
            for (int u = 0; u < 8; ++u) ca[u] = cand[nx + u];
#pragma unroll
            for (int u = 0; u < 8; ++u) {
                float d = dfast(cb[u]);
                if (d > thrm) {
                    sm.pbuf[cnt][tid] = make_int2(__float_as_int(d), i + 8 + u);
                    ++cnt;
                }
            }
            if (__any(cnt >= 9)) flush();
        }
    }
    flush();
    __syncthreads();                                 // retire push buffers

#pragma unroll
    for (int j = 0; j < KNB; ++j) sm.vals[wv][j][lane] = vals[j];
    __syncthreads();

    // every wave redundantly merges the 8 sorted value lists -> t (20th)
    float t = -INFINITY;
    {
        int p0 = 0, p1 = 0, p2 = 0, p3 = 0, p4 = 0, p5 = 0, p6 = 0, p7 = 0;
#pragma unroll 1
        for (int k = 0; k < KNB; ++k) {
            float e0 = sm.vals[0][p0][lane], e1 = sm.vals[1][p1][lane];
            float e2 = sm.vals[2][p2][lane], e3 = sm.vals[3][p3][lane];
            float e4 = sm.vals[4][p4][lane], e5 = sm.vals[5][p5][lane];
            float e6 = sm.vals[6][p6][lane], e7 = sm.vals[7][p7][lane];
            float bv = e0; int bs = 0;
            if (e1 > bv) { bv = e1; bs = 1; }
            if (e2 > bv) { bv = e2; bs = 2; }
            if (e3 > bv) { bv = e3; bs = 3; }
            if (e4 > bv) { bv = e4; bs = 4; }
            if (e5 > bv) { bv = e5; bs = 5; }
            if (e6 > bv) { bv = e6; bs = 6; }
            if (e7 > bv) { bv = e7; bs = 7; }
            t = bv;
            p0 += (bs == 0); p1 += (bs == 1); p2 += (bs == 2); p3 += (bs == 3);
            p4 += (bs == 4); p5 += (bs == 5); p6 += (bs == 6); p7 += (bs == 7);
        }
    }
    __syncthreads();                                 // retire vals (alias b)

    // phase B (R20): fast-screened streamed scan pushes u16 local idx of
    // dfast > t-MG passers (~2.5/thread); flush-style processing applies
    // EXACT dist for the d >= t filter + strict bit, appends in scan order.
    int myc = 0;
    {
        const float tm = t - MG;
        int cnt2 = 0;
        auto pbflush = [&]() {
            int ci = sm.b.pb2[0][tid];               // speculative 1-ahead
            float4 cq = cand[ci & (SEGW - 1)];
#pragma unroll
            for (int j = 0; j < NSLOT; ++j) {
                if (!__any(j < cnt2)) break;
                int ni = (j + 1 < NSLOT) ? (int)sm.b.pb2[j + 1][tid] : 0;
                float4 nq = cand[ni & (SEGW - 1)];
                if (j < cnt2) {
                    float d = dist(cq);              // exact 8-op
                    if (d >= t) {
                        if (myc < KNB)
                            sm.b.list[wv][lane][myc] =
                                (wv * SEGW + ci) | ((d > t) ? (int)0x80000000 : 0);
                        ++myc;
                    }
                }
                ci = ni; cq = nq;
            }
            cnt2 = 0;
        };
        float4 ca[8], cb[8];
#pragma unroll
        for (int u = 0; u < 8; ++u) ca[u] = cand[u];
#pragma unroll 1
        for (int i = 0; i < SEGW; i += 16) {
#pragma unroll
            for (int u = 0; u < 8; ++u) cb[u] = cand[i + 8 + u];
#pragma unroll
            for (int u = 0; u < 8; ++u) {
                float d = dfast(ca[u]);
                if (d > tm) { sm.b.pb2[cnt2][tid] = (unsigned short)(i + u); ++cnt2; }
            }
            if (__any(cnt2 >= 9)) pbflush();         // <=8 resident + 8 = 16
            const int nx = (i + 16 < SEGW) ? i + 16 : 0;   // clamp: safe
#pragma unroll
            for (int u = 0; u < 8; ++u) ca[u] = cand[nx + u];
#pragma unroll
            for (int u = 0; u < 8; ++u) {
                float d = dfast(cb[u]);
                if (d > tm) { sm.b.pb2[cnt2][tid] = (unsigned short)(i + 8 + u); ++cnt2; }
            }
            if (__any(cnt2 >= 9)) pbflush();
        }
        pbflush();
    }
    sm.b.cnt[wv][lane] = (myc < KNB) ? myc : KNB;
    __syncthreads();

    if (wv == 0) {
        int nout = 0;
#pragma unroll 1
        for (int pass = 0; pass < 2; ++pass) {       // 0: d>t, 1: d==t
#pragma unroll 1
            for (int w = 0; w < NSEG; ++w) {
                int cw = sm.b.cnt[w][lane];
#pragma unroll 1
                for (int j = 0; j < KNB; ++j) {
                    if (!__any(j < cw)) break;
                    if (j < cw) {
                        int e = sm.b.list[w][lane][j];
                        bool strict = (e < 0);
                        bool take = (pass == 0) ? strict : !strict;
                        if (take && nout < KNB) {
                            outk[nout][lane] = e & 0x7fffffff;
                            ++nout;
                        }
                    }
                }
            }
        }
    }
    __syncthreads();                                 // outk ready; b dead

    // ------------------- fused conv epilogue (R9-validated) -----------------
#pragma unroll
    for (int r = 0; r < 3; ++r) {
        int p = tid + r * 512;
        if (p < KNB * 64) {
            int k = p >> 6, pt = p & 63;
            int nb = outk[k][pt];
            float4 nq = xp[(b << 12) + nb];              // scattered (spread)
            float4 cq = xp[g0 + pt];                     // L1-hot
            sm.f.dif[k][0][pt] = __fsub_rn(nq.x, cq.x);
            sm.f.dif[k][1][pt] = __fsub_rn(nq.y, cq.y);
            sm.f.dif[k][2][pt] = __fsub_rn(nq.z, cq.z);
        }
    }
    __syncthreads();

    float dx[KNB], dy[KNB], dz[KNB];
#pragma unroll
    for (int k = 0; k < KNB; ++k) {                      // conflict-free LDS
        dx[k] = sm.f.dif[k][0][lane];
        dy[k] = sm.f.dif[k][1][lane];
        dz[k] = sm.f.dif[k][2][lane];
    }

    // conv1 eighth: channels [8*wv, 8*wv+8)
    const float4* w1fv = (const float4*)w1f;
#pragma unroll 1
    for (int cc = 0; cc < 8; ++cc) {
        int c = wv * 8 + cc;                             // uniform -> s_load
        float4 wa = w1fv[c * 2];                         // {W0,W1,W2,W3}
        float4 wb = w1fv[c * 2 + 1];                     // {W4,W5,B1',pad}
        float base = wb.z + wa.w * cx + wb.x * cy + wb.y * cz;
        float m1 = -INFINITY, s = 0.f;
#pragma unroll
        for (int k = 0; k < KNB; ++k) {
            float h = fmaf(dz[k], wa.z, fmaf(dy[k], wa.y, fmaf(dx[k], wa.x, base)));
            float r = fmaxf(0.f, h);
            m1 = fmaxf(m1, r);
            s += r;
        }
        sm.f.cat[c * 64 + lane]        = m1;
        sm.f.cat[(64 + c) * 64 + lane] = s / 20.0f;
    }
    __syncthreads();

    const size_t SEC = (size_t)NB * 64 * NPB;   // elements per output section

    // write m1/m2 rows straight from cat (coalesced 256B rows)
#pragma unroll 1
    for (int q = 0; q < 16; ++q) {
        int r  = wv * 16 + q;                   // 0..127, uniform
        int ch = r & 63;
        float* dst = out + SEC * (1 + (r >> 6)) + ((size_t)b * 64 + ch) * NPB + n0;
        dst[lane] = sm.f.cat[r * 64 + lane];
    }

    // conv2 eighth: outputs [8*wv, 8*wv+8)
    const int ob = wv * 8;                      // uniform -> s_load weights
    float acc[8];
#pragma unroll
    for (int j = 0; j < 8; ++j) acc[j] = w2b[ob + j];
#pragma unroll 4
    for (int c = 0; c < 128; ++c) {
        float v = sm.f.cat[c * 64 + lane];
        const float4* wr = (const float4*)(w2f + c * 64 + ob);
        float4 q0 = wr[0], q1 = wr[1];
        acc[0] = fmaf(v, q0.x, acc[0]);  acc[1] = fmaf(v, q0.y, acc[1]);
        acc[2] = fmaf(v, q0.z, acc[2]);  acc[3] = fmaf(v, q0.w, acc[3]);
        acc[4] = fmaf(v, q1.x, acc[4]);  acc[5] = fmaf(v, q1.y, acc[5]);
        acc[6] = fmaf(v, q1.z, acc[6]);  acc[7] = fmaf(v, q1.w, acc[7]);
    }
#pragma unroll
    for (int j = 0; j < 8; ++j) acc[j] = fmaxf(0.f, acc[j]);

    __syncthreads();                            // all waves done reading cat
#pragma unroll
    for (int j = 0; j < 8; ++j) sm.f.cat[(ob + j) * 64 + lane] = acc[j];
    __syncthreads();
#pragma unroll 1
    for (int q = 0; q < 8; ++q) {
        int oo = wv * 8 + q;
        out[((size_t)b * 64 + oo) * NPB + n0 + lane] = sm.f.cat[oo * 64 + lane];
    }
}

extern "C" void kernel_launch(void* const* d_in, const int* in_sizes, int n_in,
                              void* d_out, int out_size, void* d_ws, size_t ws_size,
                              hipStream_t stream) {
    const float* x   = (const float*)d_in[0];
    const float* w1  = (const float*)d_in[1];
    const float* b1  = (const float*)d_in[2];
    const float* g1  = (const float*)d_in[3];
    const float* be1 = (const float*)d_in[4];
    const float* rm1 = (const float*)d_in[5];
    const float* rv1 = (const float*)d_in[6];
    const float* w2  = (const float*)d_in[7];
    const float* b2  = (const float*)d_in[8];
    const float* g2  = (const float*)d_in[9];
    const float* be2 = (const float*)d_in[10];
    const float* rm2 = (const float*)d_in[11];
    const float* rv2 = (const float*)d_in[12];

    char*   ws  = (char*)d_ws;
    float4* xp  = (float4*)ws;                      // 512 KB
    float*  w1f = (float*)(ws + 512 * 1024);        // 2 KB
    float*  w2f = w1f + 64 * 8;                     // 32 KB
    float*  w2b = w2f + 64 * 128;                   // 256 B

    pack_prep_kernel<<<NPTS / 256, 256, 0, stream>>>(
        x, xp, w1, b1, g1, be1, rm1, rv1, w2, b2, g2, be2, rm2, rv2,
        w1f, w2f, w2b);
    knnfuse_kernel<<<NPTS / 64, 512, 0, stream>>>(xp, w1f, w2f, w2b,
                                                  (float*)d_out);
}